// Round 1
// baseline (505.270 us; speedup 1.0000x reference)
//
#include <hip/hip_runtime.h>

// RoPE: out_even = even*cos - odd*sin; out_odd = even*sin + odd*cos
// xq, xk: (B=2, S=4096, D=4096) f32. freqs_cis: (8192, 2048, 2) f32 = rows of
// 4096 floats [cos0,sin0,cos1,sin1,...]. A float4 of x at within-row float4
// index j needs exactly the freqs float4 at index j of row (start+s).

#define S_LEN 4096
#define ROW4  1024   // 4096 floats per row / 4 per float4

__global__ __launch_bounds__(256) void rope_kernel(
    const float4* __restrict__ xq,
    const float4* __restrict__ xk,
    const float4* __restrict__ freqs,
    const int*    __restrict__ start_p,
    float4* __restrict__ outq,
    float4* __restrict__ outk,
    long long n4)
{
    long long i = (long long)blockIdx.x * blockDim.x + threadIdx.x;
    if (i >= n4) return;

    int row  = (int)(i >> 10);      // b*S + s  (D/4 = 1024 float4 per row)
    int col4 = (int)(i & (ROW4 - 1));
    int s    = row & (S_LEN - 1);   // S = 4096 (power of 2)
    int pos  = *start_p + s;

    float4 fc = freqs[(long long)pos * ROW4 + col4];
    float4 q  = xq[i];
    float4 k  = xk[i];

    float4 oq, ok;
    oq.x = q.x * fc.x - q.y * fc.y;
    oq.y = q.x * fc.y + q.y * fc.x;
    oq.z = q.z * fc.z - q.w * fc.w;
    oq.w = q.z * fc.w + q.w * fc.z;

    ok.x = k.x * fc.x - k.y * fc.y;
    ok.y = k.x * fc.y + k.y * fc.x;
    ok.z = k.z * fc.z - k.w * fc.w;
    ok.w = k.z * fc.w + k.w * fc.z;

    outq[i] = oq;
    outk[i] = ok;
}

extern "C" void kernel_launch(void* const* d_in, const int* in_sizes, int n_in,
                              void* d_out, int out_size, void* d_ws, size_t ws_size,
                              hipStream_t stream) {
    const float4* xq    = (const float4*)d_in[0];
    const float4* xk    = (const float4*)d_in[1];
    const float4* fc    = (const float4*)d_in[2];
    const int*    start = (const int*)d_in[3];

    long long n  = (long long)in_sizes[0];   // 33,554,432 elements per tensor
    long long n4 = n / 4;                    // 8,388,608 float4 per tensor

    float4* outq = (float4*)d_out;
    float4* outk = (float4*)((float*)d_out + n);

    int block = 256;
    long long grid = (n4 + block - 1) / block;   // 32768 blocks

    rope_kernel<<<(dim3)(unsigned)grid, block, 0, stream>>>(
        xq, xk, fc, start, outq, outk, n4);
}